// Round 8
// baseline (167.126 us; speedup 1.0000x reference)
//
#include <hip/hip_runtime.h>

// YOLO decode = batched [255 x 5776] transpose + elementwise.
// R8: barrier-free per-wave transpose. Each wave owns a 64ch x 16sp tile and a
//     private 16x68-float LDS slice (4352B). No __syncthreads anywhere; LDS RAW
//     is wave-internal (lgkmcnt). Rows rotated by phi=s&3 so global f4 stores
//     stay 16B-aligned despite the 1020B output row stride; lane m=15 writes
//     the 4 wrap floats scalar. 8 blocks/CU x 4 waves = 32 waves/CU.

#define ATTRS 85
#define CH    255
#define G_    76
#define SP    5776          // 361 * 16
#define STRIDE_F 8.0f
#define SUBW  16
#define NSUB  361
#define WPB   4             // waves per block
#define SGRPS 91            // ceil(361/4)
#define TPB   256
#define LSTR  68            // LDS row stride (floats): 16B-aligned, conflict-free
#define SLICE (SUBW * LSTR) // 1088 floats per wave slice

typedef float f4 __attribute__((ext_vector_type(4)));

__device__ __forceinline__ float decode1(float val, int attr, int s,
                                         float ax, float ay) {
    if (attr == 2) return __expf(val) * ax;
    if (attr == 3) return __expf(val) * ay;
    const float sg = __builtin_amdgcn_rcpf(1.0f + __expf(-val));
    if (attr == 0) return (sg + (float)(s % G_)) * STRIDE_F;
    if (attr == 1) return (sg + (float)(s / G_)) * STRIDE_F;
    return sg;
}

__global__ __launch_bounds__(TPB, 8) void yolo_decode_kernel(
        const float* __restrict__ pred,
        const float* __restrict__ anchors,
        float* __restrict__ out) {
    __shared__ float lds[WPB * SLICE];   // 4 * 1088 * 4 = 17408 B

    const int tid = threadIdx.x;
    const int l   = tid & 63;
    const int wid = tid >> 6;

    const int bid  = blockIdx.x;
    const int sgrp = bid % SGRPS;
    const int r2   = bid / SGRPS;
    const int cblk = r2 & 3;
    const int b    = r2 >> 2;

    const int sub = sgrp * WPB + wid;    // wave's s-subtile
    if (sub >= NSUB) return;             // uniform per wave; no barriers exist
    const int s0 = sub * SUBW;
    const int c0 = cblk << 6;            // 0,64,128,192 (last block: 63 channels)

    const float a0x = anchors[0], a0y = anchors[1];
    const float a1x = anchors[2], a1y = anchors[3];
    const float a2x = anchors[4], a2y = anchors[5];

    float* const slb = lds + wid * SLICE;
    const float* const src = pred + (size_t)b * ((size_t)CH * SP) + s0;

    const int co_l = l >> 2;             // 0..15: channel sub-index per iter
    const int sl   = (l & 3) * 4;        // 0,4,8,12: f4 chunk within subtile

    // ---- read: 4 independent f4 loads (16 rows x 64B per instruction) ----
    f4 v0 = {0,0,0,0}, v1 = {0,0,0,0}, v2 = {0,0,0,0}, v3 = {0,0,0,0};
    {
        const int cA = c0 + co_l;
        const int cB = c0 + 16 + co_l;
        const int cC = c0 + 32 + co_l;
        const int cD = c0 + 48 + co_l;                 // ==255 only when cblk=3,co_l=15
        v0 = *(const f4*)(src + (size_t)cA * SP + sl);
        v1 = *(const f4*)(src + (size_t)cB * SP + sl);
        v2 = *(const f4*)(src + (size_t)cC * SP + sl);
        if (cD < CH) v3 = *(const f4*)(src + (size_t)cD * SP + sl);
    }

    // ---- decode + rotated LDS scatter ----
    // row r = sl+e; phi(row) = r&3 = e; word = (co - e) & 63.
    // Bank audit per instr: 16*(q&1) + 4P + clo - shift -> 32 banks, 2-way. Free.
    #pragma unroll
    for (int it = 0; it < 4; ++it) {
        const int co = it * 16 + co_l;
        const int c  = c0 + co;          // 255 possible (garbage column, never stored)
        const int a    = c / ATTRS;
        const int attr = c - a * ATTRS;
        const float ax = (a == 0) ? a0x : (a == 1) ? a1x : a2x;
        const float ay = (a == 0) ? a0y : (a == 1) ? a1y : a2y;
        const f4 v = (it == 0) ? v0 : (it == 1) ? v1 : (it == 2) ? v2 : v3;
        #pragma unroll
        for (int e = 0; e < 4; ++e) {
            const int s = s0 + sl + e;
            const float rv = decode1(v[e], attr, s, ax, ay);
            slb[(sl + e) * LSTR + ((co - e) & 63)] = rv;
        }
    }
    // (compiler inserts lgkmcnt before the dependent ds_reads below)

    // ---- gather + nt-store: aligned f4 for m<15, 4 scalars on m=15 ----
    const int P = l >> 4;                // 0..3
    const int m = l & 15;
    const size_t orow0 = (size_t)b * ((size_t)SP * CH) + (size_t)s0 * CH + c0;
    #pragma unroll
    for (int it = 0; it < 4; ++it) {
        const int s_loc = it * 4 + P;
        const int phi   = P;             // (it*4+P)&3 == P
        const float* lr = slb + s_loc * LSTR;
        const f4 w = *(const f4*)(lr + 4 * m);          // aligned b128
        float* prow = out + orow0 + (size_t)s_loc * CH;
        if (m < 15) {
            // floats [phi+4m, phi+4m+4): global index ≡ 0 mod 4 -> aligned f4
            __builtin_nontemporal_store(w, (f4*)(prow + phi + 4 * m));
        } else {
            // words 60..63 hold floats {60+phi..63} ++ {0..phi-1}
            #pragma unroll
            for (int wd = 0; wd < 4; ++wd) {
                const int f = (60 + wd + phi) & 63;
                if (c0 + f < CH)                          // skips garbage c=255
                    __builtin_nontemporal_store(w[wd], prow + f);
            }
        }
    }
}

extern "C" void kernel_launch(void* const* d_in, const int* in_sizes, int n_in,
                              void* d_out, int out_size, void* d_ws, size_t ws_size,
                              hipStream_t stream) {
    const float* pred    = (const float*)d_in[0];
    const float* anchors = (const float*)d_in[1];
    float* out = (float*)d_out;

    const int grid = 32 * 4 * SGRPS;   // b x cblk x sgroup = 11648 blocks
    yolo_decode_kernel<<<grid, TPB, 0, stream>>>(pred, anchors, out);
}

// Round 9
// 73.896 us; speedup vs baseline: 2.2616x; 2.2616x over previous
//
#include <hip/hip_runtime.h>

// YOLO decode = batched [255 x 5776] transpose + elementwise.
// R9: R6 structure, S_TILE=128 via bf16 LDS tile (128 x 256 ushort = 64KB
//     static -> still 2 blocks/CU, 32 waves/CU). 512B/channel-row reads.
//     Scatter col' = (c + 2*(row>>2)) & 255: conflict-free writes, 2-way gather.
//     Whole output rows per block, contiguous aligned nt f4 stores (R8 lesson).
//     bf16 RNE round-trip err <= ~11 abs on this data; threshold 68.16.

#define BATCH   32
#define ATTRS   85
#define CH      255
#define G_      76
#define SP      5776          // 128*45 + 16
#define STRIDE_F 8.0f
#define S_TILE  128
#define TPB     1024
#define TILES_PER_B 46        // 45 full + one 16-wide
#define NF4_READ (CH * (S_TILE / 4))   // 255*32 = 8160
#define LROW    256           // padded LDS row stride (bf16 elems)

typedef float f4 __attribute__((ext_vector_type(4)));

static __device__ __forceinline__ unsigned short f2bf(float f) {
    union { float f; unsigned u; } x; x.f = f;
    unsigned u = x.u + 0x7FFFu + ((x.u >> 16) & 1u);   // RNE
    return (unsigned short)(u >> 16);
}
static __device__ __forceinline__ float bf2f(unsigned short h) {
    union { unsigned u; float f; } x; x.u = ((unsigned)h) << 16;
    return x.f;
}

__device__ __forceinline__ float decode1(float val, int attr, int s,
                                         float ax, float ay) {
    if (attr == 2) return __expf(val) * ax;
    if (attr == 3) return __expf(val) * ay;
    const float sg = __builtin_amdgcn_rcpf(1.0f + __expf(-val));
    if (attr == 0) return (sg + (float)(s % G_)) * STRIDE_F;
    if (attr == 1) return (sg + (float)(s / G_)) * STRIDE_F;
    return sg;
}

__global__ __launch_bounds__(TPB, 8) void yolo_decode_kernel(
        const float* __restrict__ pred,
        const float* __restrict__ anchors,
        float* __restrict__ out) {
    __shared__ unsigned short lds[S_TILE * LROW];   // 65536 B

    const int tid = threadIdx.x;
    const int bid = blockIdx.x;
    const int b   = bid / TILES_PER_B;
    const int t   = bid - b * TILES_PER_B;
    const int s0  = t * S_TILE;
    const int sw  = (t == TILES_PER_B - 1) ? (SP - s0) : S_TILE;  // 128 or 16

    const float a0x = anchors[0], a0y = anchors[1];
    const float a1x = anchors[2], a1y = anchors[3];
    const float a2x = anchors[4], a2y = anchors[5];

    // ---- read + decode + bf16 scatter ----
    // wave phase: 32 lanes share channel c, sl4 = 4*l -> 512B contiguous read.
    // scatter: row r=sl4+e, col' = (c + 2*(r>>2)) & 255
    //   -> word = r*128 + c/2 + l (mod 32 -> all 32 banks, conflict-free).
    const float* __restrict__ src = pred + (size_t)b * ((size_t)CH * SP) + s0;
    for (int j = tid; j < NF4_READ; j += TPB) {
        const int c   = j >> 5;            // 0..254
        const int sl4 = (j & 31) << 2;     // 0..124
        if (sl4 >= sw) continue;           // trims only the 16-wide partial tile

        f4 v = *(const f4*)(src + (size_t)c * SP + sl4);

        const int a    = c / ATTRS;
        const int attr = c - a * ATTRS;
        const float ax = (a == 0) ? a0x : (a == 1) ? a1x : a2x;
        const float ay = (a == 0) ? a0y : (a == 1) ? a1y : a2y;

        #pragma unroll
        for (int e = 0; e < 4; ++e) {
            const int r = sl4 + e;
            const float rv = decode1(v[e], attr, s0 + r, ax, ay);
            const int colp = (c + 2 * (r >> 2)) & 255;
            lds[r * LROW + colp] = f2bf(rv);
        }
    }
    __syncthreads();

    // ---- gather (bf16 -> f32) + contiguous nt f4 stores ----
    const int nf4w = (sw * CH) >> 2;       // 8160 full, 1020 partial
    float* __restrict__ dst = out + (size_t)b * ((size_t)SP * CH)
                                  + (size_t)s0 * CH;
    for (int j = tid; j < nf4w; j += TPB) {
        const int idx = j << 2;
        f4 w;
        #pragma unroll
        for (int e = 0; e < 4; ++e) {
            const int ie = idx + e;
            const int sl = ie / CH;                // magic-mul div by 255
            const int c  = ie - sl * CH;
            const int colp = (c + 2 * (sl >> 2)) & 255;
            w[e] = bf2f(lds[sl * LROW + colp]);
        }
        __builtin_nontemporal_store(w, (f4*)(dst + idx));
    }
}

extern "C" void kernel_launch(void* const* d_in, const int* in_sizes, int n_in,
                              void* d_out, int out_size, void* d_ws, size_t ws_size,
                              hipStream_t stream) {
    const float* pred    = (const float*)d_in[0];
    const float* anchors = (const float*)d_in[1];
    float* out = (float*)d_out;

    const int grid = BATCH * TILES_PER_B;   // 32 * 46 = 1472
    yolo_decode_kernel<<<grid, TPB, 0, stream>>>(pred, anchors, out);
}

// Round 10
// 73.151 us; speedup vs baseline: 2.2847x; 1.0102x over previous
//
#include <hip/hip_runtime.h>

// YOLO decode = batched [255 x 5776] transpose + elementwise.
// R10: R6 geometry (S_TILE=64, TPB=1024, flat f32 LDS tile, conflict-free
//      scatter, contiguous nt f4 stores) + persistent blocks (512 = 2/CU) with
//      register prefetch across RAW s_barriers (no __syncthreads: hipcc drains
//      vmcnt(0) there, which would kill loads-in-flight). Loads are issued
//      BEFORE the store phase so the auto vmcnt wait before next decode counts
//      only the loads. LDS W(k+1)-after-R(k) is safe: each wave's ds_read
//      values are consumed (lgkmcnt-waited) before it reaches barrier 2.

#define BATCH   32
#define ATTRS   85
#define CH      255
#define G_      76
#define SP      5776          // 64*90 + 16
#define STRIDE_F 8.0f
#define S_TILE  64
#define TPB     1024
#define TILES_PER_B 91        // 90 full + one 16-wide
#define NTILES  (BATCH * TILES_PER_B)   // 2912
#define NBLK    512                     // 2 blocks/CU resident

typedef float f4 __attribute__((ext_vector_type(4)));

__device__ __forceinline__ float decode1(float val, int attr, int s,
                                         float ax, float ay) {
    if (attr == 2) return __expf(val) * ax;
    if (attr == 3) return __expf(val) * ay;
    const float sg = __builtin_amdgcn_rcpf(1.0f + __expf(-val));
    if (attr == 0) return (sg + (float)(s % G_)) * STRIDE_F;
    if (attr == 1) return (sg + (float)(s / G_)) * STRIDE_F;
    return sg;
}

__global__ __launch_bounds__(TPB, 8) void yolo_decode_kernel(
        const float* __restrict__ pred,
        const float* __restrict__ anchors,
        float* __restrict__ out) {
    __shared__ float lds[S_TILE * CH];   // 65280 B, single buffer

    const int tid = threadIdx.x;

    const float a0x = anchors[0], a0y = anchors[1];
    const float a1x = anchors[2], a1y = anchors[3];
    const float a2x = anchors[4], a2y = anchors[5];

    // fixed per-thread geometry (R6's conflict-free mapping, unrolled):
    // sl = 4*((tid>>2)&15) is iteration-invariant; channels c0 + {0,64,128,192}.
    const int c0 = ((tid >> 6) << 2) | (tid & 3);   // 0..63
    const int sl = ((tid >> 2) & 15) << 2;          // 0..60
    const bool act3 = (c0 + 192) < CH;              // c0 < 63

    const int cA = c0,       aA = cA / ATTRS, atA = cA - aA * ATTRS;
    const int cB = c0 + 64,  aB = cB / ATTRS, atB = cB - aB * ATTRS;
    const int cC = c0 + 128, aC = cC / ATTRS, atC = cC - aC * ATTRS;
    const int cD = c0 + 192, aD = cD / ATTRS, atD = cD - aD * ATTRS;
    const float axA = (aA == 0) ? a0x : (aA == 1) ? a1x : a2x;
    const float ayA = (aA == 0) ? a0y : (aA == 1) ? a1y : a2y;
    const float axB = (aB == 0) ? a0x : (aB == 1) ? a1x : a2x;
    const float ayB = (aB == 0) ? a0y : (aB == 1) ? a1y : a2y;
    const float axC = (aC == 0) ? a0x : (aC == 1) ? a1x : a2x;
    const float ayC = (aC == 0) ? a0y : (aC == 1) ? a1y : a2y;
    const float axD = (aD == 0) ? a0x : (aD == 1) ? a1x : a2x;
    const float ayD = (aD == 0) ? a0y : (aD == 1) ? a1y : a2y;

    // ---- prologue: issue first tile's loads ----
    int tk = blockIdx.x;                    // < 512 < NTILES
    int b  = tk / TILES_PER_B;
    int t  = tk - b * TILES_PER_B;
    int s0 = t * S_TILE;
    int sw = (t == TILES_PER_B - 1) ? (SP - s0) : S_TILE;   // 64 or 16
    const float* src = pred + (size_t)b * ((size_t)CH * SP) + s0 + sl;

    f4 v0 = {0,0,0,0}, v1 = {0,0,0,0}, v2 = {0,0,0,0}, v3 = {0,0,0,0};
    if (sl < sw) {
        v0 = *(const f4*)(src + (size_t)cA * SP);
        v1 = *(const f4*)(src + (size_t)cB * SP);
        v2 = *(const f4*)(src + (size_t)cC * SP);
        if (act3) v3 = *(const f4*)(src + (size_t)cD * SP);
    }

    for (;;) {
        const int cb = b, cs0 = s0, csw = sw;

        // ---- decode current tile (vmcnt wait on v* lands here) -> LDS ----
        if (sl < csw) {
            #pragma unroll
            for (int e = 0; e < 4; ++e) {
                const int r = sl + e, s = cs0 + r;
                lds[r * CH + cA] = decode1(v0[e], atA, s, axA, ayA);
                lds[r * CH + cB] = decode1(v1[e], atB, s, axB, ayB);
                lds[r * CH + cC] = decode1(v2[e], atC, s, axC, ayC);
                if (act3) lds[r * CH + cD] = decode1(v3[e], atD, s, axD, ayD);
            }
        }

        // ---- issue next tile's loads (stay in flight across both barriers) ----
        const int ntk = tk + NBLK;
        const bool more = (ntk < NTILES);
        if (more) {
            b  = ntk / TILES_PER_B;
            t  = ntk - b * TILES_PER_B;
            s0 = t * S_TILE;
            sw = (t == TILES_PER_B - 1) ? (SP - s0) : S_TILE;
            src = pred + (size_t)b * ((size_t)CH * SP) + s0 + sl;
            if (sl < sw) {
                v0 = *(const f4*)(src + (size_t)cA * SP);
                v1 = *(const f4*)(src + (size_t)cB * SP);
                v2 = *(const f4*)(src + (size_t)cC * SP);
                if (act3) v3 = *(const f4*)(src + (size_t)cD * SP);
            }
        }

        // barrier 1: ds_writes drained (lgkmcnt only — vmcnt stays outstanding)
        asm volatile("s_waitcnt lgkmcnt(0)" ::: "memory");
        __builtin_amdgcn_sched_barrier(0);
        __builtin_amdgcn_s_barrier();
        __builtin_amdgcn_sched_barrier(0);

        // ---- store phase: contiguous [csw*255] floats, aligned nt f4 ----
        float* __restrict__ dst = out + (size_t)cb * ((size_t)SP * CH)
                                      + (size_t)cs0 * CH;
        const int nf4w = (csw * CH) >> 2;    // 4080 full, 1020 partial
        for (int j = tid; j < nf4w; j += TPB) {
            f4 w = *(const f4*)(lds + 4 * j);
            __builtin_nontemporal_store(w, (f4*)(dst + 4 * j));
        }

        if (!more) break;

        // barrier 2: every wave consumed its ds_reads already (data-dep wait
        // before its stores), so after this barrier LDS is safe to overwrite.
        asm volatile("" ::: "memory");
        __builtin_amdgcn_sched_barrier(0);
        __builtin_amdgcn_s_barrier();
        __builtin_amdgcn_sched_barrier(0);

        tk = ntk;
    }
}

extern "C" void kernel_launch(void* const* d_in, const int* in_sizes, int n_in,
                              void* d_out, int out_size, void* d_ws, size_t ws_size,
                              hipStream_t stream) {
    const float* pred    = (const float*)d_in[0];
    const float* anchors = (const float*)d_in[1];
    float* out = (float*)d_out;

    yolo_decode_kernel<<<NBLK, TPB, 0, stream>>>(pred, anchors, out);
}

// Round 11
// 68.635 us; speedup vs baseline: 2.4350x; 1.0658x over previous
//
#include <hip/hip_runtime.h>

// YOLO decode = batched [255 x 5776] transpose + elementwise.
// R11: R6 bulk-sync structure (best so far, 68.3us) + R10's unrolled per-thread
//      geometry (VALU 26->14%) + bijective XCD swizzle: grid 2912 = 8*364,
//      364 = 4*91 -> XCD x owns batches 4x..4x+3; adjacent tiles (which share
//      the 64B-straddled boundary lines on odd channels, ~95MB total) become
//      same-XCD L2 hits instead of L3 traffic.

#define BATCH   32
#define ATTRS   85
#define CH      255
#define G_      76
#define SP      5776          // 64*90 + 16
#define STRIDE_F 8.0f
#define S_TILE  64
#define TPB     1024
#define TILES_PER_B 91        // 90 full + one 16-wide
#define NTILES  (BATCH * TILES_PER_B)   // 2912 = 8 * 364

typedef float f4 __attribute__((ext_vector_type(4)));

__device__ __forceinline__ float decode1(float val, int attr, int s,
                                         float ax, float ay) {
    if (attr == 2) return __expf(val) * ax;
    if (attr == 3) return __expf(val) * ay;
    const float sg = __builtin_amdgcn_rcpf(1.0f + __expf(-val));
    if (attr == 0) return (sg + (float)(s % G_)) * STRIDE_F;
    if (attr == 1) return (sg + (float)(s / G_)) * STRIDE_F;
    return sg;
}

__global__ __launch_bounds__(TPB, 8) void yolo_decode_kernel(
        const float* __restrict__ pred,
        const float* __restrict__ anchors,
        float* __restrict__ out) {
    __shared__ float lds[S_TILE * CH];   // 65280 B

    const int tid = threadIdx.x;

    // ---- bijective XCD swizzle: xcd = bid&7 owns logical tiles [xcd*364, ..) ----
    const int bid = blockIdx.x;
    const int xcd = bid & 7;
    const int sub = bid >> 3;            // 0..363
    const int b   = (xcd << 2) + sub / TILES_PER_B;   // 364 = 4*91
    const int t   = sub % TILES_PER_B;
    const int s0  = t * S_TILE;
    const int sw  = (t == TILES_PER_B - 1) ? (SP - s0) : S_TILE;  // 64 or 16

    const float a0x = anchors[0], a0y = anchors[1];
    const float a1x = anchors[2], a1y = anchors[3];
    const float a2x = anchors[4], a2y = anchors[5];

    // fixed per-thread geometry (conflict-free scatter, unrolled):
    // wave = 4 channels x 16 sl-chunks; banks (c - sl - e) mod 32 cover all 32.
    const int c0 = ((tid >> 6) << 2) | (tid & 3);   // 0..63
    const int sl = ((tid >> 2) & 15) << 2;          // 0..60
    const bool act3 = (c0 + 192) < CH;

    const int cA = c0,       aA = cA / ATTRS, atA = cA - aA * ATTRS;
    const int cB = c0 + 64,  aB = cB / ATTRS, atB = cB - aB * ATTRS;
    const int cC = c0 + 128, aC = cC / ATTRS, atC = cC - aC * ATTRS;
    const int cD = c0 + 192, aD = cD / ATTRS, atD = cD - aD * ATTRS;
    const float axA = (aA == 0) ? a0x : (aA == 1) ? a1x : a2x;
    const float ayA = (aA == 0) ? a0y : (aA == 1) ? a1y : a2y;
    const float axB = (aB == 0) ? a0x : (aB == 1) ? a1x : a2x;
    const float ayB = (aB == 0) ? a0y : (aB == 1) ? a1y : a2y;
    const float axC = (aC == 0) ? a0x : (aC == 1) ? a1x : a2x;
    const float ayC = (aC == 0) ? a0y : (aC == 1) ? a1y : a2y;
    const float axD = (aD == 0) ? a0x : (aD == 1) ? a1x : a2x;
    const float ayD = (aD == 0) ? a0y : (aD == 1) ? a1y : a2y;

    // ---- read: 4 coalesced f4 loads (4 rows x 256B per wave) ----
    const float* __restrict__ src = pred + (size_t)b * ((size_t)CH * SP) + s0 + sl;
    f4 v0 = {0,0,0,0}, v1 = {0,0,0,0}, v2 = {0,0,0,0}, v3 = {0,0,0,0};
    if (sl < sw) {
        v0 = *(const f4*)(src + (size_t)cA * SP);
        v1 = *(const f4*)(src + (size_t)cB * SP);
        v2 = *(const f4*)(src + (size_t)cC * SP);
        if (act3) v3 = *(const f4*)(src + (size_t)cD * SP);
    }

    // ---- decode -> LDS scatter ----
    if (sl < sw) {
        #pragma unroll
        for (int e = 0; e < 4; ++e) {
            const int r = sl + e, s = s0 + r;
            lds[r * CH + cA] = decode1(v0[e], atA, s, axA, ayA);
            lds[r * CH + cB] = decode1(v1[e], atB, s, axB, ayB);
            lds[r * CH + cC] = decode1(v2[e], atC, s, axC, ayC);
            if (act3) lds[r * CH + cD] = decode1(v3[e], atD, s, axD, ayD);
        }
    }
    __syncthreads();

    // ---- store: contiguous [sw*255] floats, aligned nt f4 ----
    float* __restrict__ dst = out + (size_t)b * ((size_t)SP * CH)
                                  + (size_t)s0 * CH;
    const int nf4w = (sw * CH) >> 2;    // 4080 full, 1020 partial
    for (int j = tid; j < nf4w; j += TPB) {
        f4 w = *(const f4*)(lds + 4 * j);
        __builtin_nontemporal_store(w, (f4*)(dst + 4 * j));
    }
}

extern "C" void kernel_launch(void* const* d_in, const int* in_sizes, int n_in,
                              void* d_out, int out_size, void* d_ws, size_t ws_size,
                              hipStream_t stream) {
    const float* pred    = (const float*)d_in[0];
    const float* anchors = (const float*)d_in[1];
    float* out = (float*)d_out;

    yolo_decode_kernel<<<NTILES, TPB, 0, stream>>>(pred, anchors, out);
}

// Round 12
// 63.428 us; speedup vs baseline: 2.6349x; 1.0821x over previous
//
#include <hip/hip_runtime.h>

// YOLO decode = batched [255 x 5776] transpose + elementwise.
// R12: stream-count test. S_TILE=32 + TPB=512 -> 4 blocks/CU (130KB LDS),
//      doubling independent phase-streams per CU vs R11, with XCD swizzle
//      held (5792 = 8*724, 724 = 4*181: XCD x owns batches 4x..4x+3) so the
//      tile-boundary lines stay L2-shared and fetch doesn't regress to R4's.
//      Same conflict-free scatter, unrolled geometry, contiguous nt stores.

#define BATCH   32
#define ATTRS   85
#define CH      255
#define G_      76
#define SP      5776          // 32*180 + 16
#define STRIDE_F 8.0f
#define S_TILE  32
#define TPB     512
#define TILES_PER_B 181       // 180 full + one 16-wide
#define NTILES  (BATCH * TILES_PER_B)   // 5792 = 8 * 724

typedef float f4 __attribute__((ext_vector_type(4)));

__device__ __forceinline__ float decode1(float val, int attr, int s,
                                         float ax, float ay) {
    if (attr == 2) return __expf(val) * ax;
    if (attr == 3) return __expf(val) * ay;
    const float sg = __builtin_amdgcn_rcpf(1.0f + __expf(-val));
    if (attr == 0) return (sg + (float)(s % G_)) * STRIDE_F;
    if (attr == 1) return (sg + (float)(s / G_)) * STRIDE_F;
    return sg;
}

__global__ __launch_bounds__(TPB, 8) void yolo_decode_kernel(
        const float* __restrict__ pred,
        const float* __restrict__ anchors,
        float* __restrict__ out) {
    __shared__ float lds[S_TILE * CH];   // 32640 B -> 4 blocks/CU

    const int tid = threadIdx.x;

    // ---- bijective XCD swizzle ----
    const int bid = blockIdx.x;
    const int xcd = bid & 7;
    const int sub = bid >> 3;                 // 0..723
    const int bq  = sub / TILES_PER_B;        // 0..3
    const int b   = (xcd << 2) + bq;
    const int t   = sub - bq * TILES_PER_B;
    const int s0  = t * S_TILE;
    const int sw  = (t == TILES_PER_B - 1) ? (SP - s0) : S_TILE;  // 32 or 16

    const float a0x = anchors[0], a0y = anchors[1];
    const float a1x = anchors[2], a1y = anchors[3];
    const float a2x = anchors[4], a2y = anchors[5];

    // per-thread geometry: 32-lane phase = 4 channels x 8 sl-chunks
    // -> LDS-write banks (c - sl - e) mod 32 cover all 32. (R1/R4: measured 0.)
    const int c0 = ((tid >> 5) << 2) | (tid & 3);   // 0..63
    const int sl = ((tid >> 2) & 7) << 2;           // 0..28
    const bool act3 = (c0 + 192) < CH;

    const int cA = c0,       aA = cA / ATTRS, atA = cA - aA * ATTRS;
    const int cB = c0 + 64,  aB = cB / ATTRS, atB = cB - aB * ATTRS;
    const int cC = c0 + 128, aC = cC / ATTRS, atC = cC - aC * ATTRS;
    const int cD = c0 + 192, aD = cD / ATTRS, atD = cD - aD * ATTRS;
    const float axA = (aA == 0) ? a0x : (aA == 1) ? a1x : a2x;
    const float ayA = (aA == 0) ? a0y : (aA == 1) ? a1y : a2y;
    const float axB = (aB == 0) ? a0x : (aB == 1) ? a1x : a2x;
    const float ayB = (aB == 0) ? a0y : (aB == 1) ? a1y : a2y;
    const float axC = (aC == 0) ? a0x : (aC == 1) ? a1x : a2x;
    const float ayC = (aC == 0) ? a0y : (aC == 1) ? a1y : a2y;
    const float axD = (aD == 0) ? a0x : (aD == 1) ? a1x : a2x;
    const float ayD = (aD == 0) ? a0y : (aD == 1) ? a1y : a2y;

    // ---- read: 4 coalesced f4 loads ----
    const float* __restrict__ src = pred + (size_t)b * ((size_t)CH * SP) + s0 + sl;
    f4 v0 = {0,0,0,0}, v1 = {0,0,0,0}, v2 = {0,0,0,0}, v3 = {0,0,0,0};
    if (sl < sw) {
        v0 = *(const f4*)(src + (size_t)cA * SP);
        v1 = *(const f4*)(src + (size_t)cB * SP);
        v2 = *(const f4*)(src + (size_t)cC * SP);
        if (act3) v3 = *(const f4*)(src + (size_t)cD * SP);
    }

    // ---- decode -> LDS scatter ----
    if (sl < sw) {
        #pragma unroll
        for (int e = 0; e < 4; ++e) {
            const int r = sl + e, s = s0 + r;
            lds[r * CH + cA] = decode1(v0[e], atA, s, axA, ayA);
            lds[r * CH + cB] = decode1(v1[e], atB, s, axB, ayB);
            lds[r * CH + cC] = decode1(v2[e], atC, s, axC, ayC);
            if (act3) lds[r * CH + cD] = decode1(v3[e], atD, s, axD, ayD);
        }
    }
    __syncthreads();

    // ---- store: contiguous [sw*255] floats, aligned nt f4 ----
    float* __restrict__ dst = out + (size_t)b * ((size_t)SP * CH)
                                  + (size_t)s0 * CH;
    const int nf4w = (sw * CH) >> 2;    // 2040 full, 1020 partial
    for (int j = tid; j < nf4w; j += TPB) {
        f4 w = *(const f4*)(lds + 4 * j);
        __builtin_nontemporal_store(w, (f4*)(dst + 4 * j));
    }
}

extern "C" void kernel_launch(void* const* d_in, const int* in_sizes, int n_in,
                              void* d_out, int out_size, void* d_ws, size_t ws_size,
                              hipStream_t stream) {
    const float* pred    = (const float*)d_in[0];
    const float* anchors = (const float*)d_in[1];
    float* out = (float*)d_out;

    yolo_decode_kernel<<<NTILES, TPB, 0, stream>>>(pred, anchors, out);
}